// Round 3
// baseline (208.259 us; speedup 1.0000x reference)
//
#include <hip/hip_runtime.h>
#include <hip/hip_bf16.h>

// Problem constants (from reference): B,T,L,R,E,F
#define B_ 8
#define T_ 16
#define L_ 128
#define R_ 1024
#define E_ 5
#define F_ 512

typedef short short8 __attribute__((ext_vector_type(8)));
typedef float floatx4 __attribute__((ext_vector_type(4)));

// fp32 -> bf16 bits, round-half-up
__device__ __forceinline__ unsigned short f2bf(float f) {
  unsigned u = __float_as_uint(f);
  return (unsigned short)((u + 0x8000u) >> 16);
}

__device__ __forceinline__ short8 pack8(floatx4 lo, floatx4 hi) {
  short8 v;
  v[0] = (short)f2bf(lo[0]); v[1] = (short)f2bf(lo[1]);
  v[2] = (short)f2bf(lo[2]); v[3] = (short)f2bf(lo[3]);
  v[4] = (short)f2bf(hi[0]); v[5] = (short)f2bf(hi[1]);
  v[6] = (short)f2bf(hi[2]); v[7] = (short)f2bf(hi[3]);
  return v;
}

// ---------------------------------------------------------------------------
// Kernel 1: rot = QR(pre_rot).Q (LAPACK Householder convention), then
// new_lig[b,t,l,:] = rot[b,t] @ lig_coord[b,l] + trans[b,t].
// ---------------------------------------------------------------------------
__global__ void prep_kernel(const float* __restrict__ lig_coord,
                            const float* __restrict__ pre_rot,
                            const float* __restrict__ trans,
                            float* __restrict__ new_lig) {
  int bt = blockIdx.x;
  __shared__ float Qs[3][3];
  if (threadIdx.x == 0) {
    float a[3][3], q[3][3];
    #pragma unroll
    for (int i = 0; i < 3; ++i)
      #pragma unroll
      for (int j = 0; j < 3; ++j) {
        a[i][j] = pre_rot[(bt * 3 + i) * 3 + j];
        q[i][j] = (i == j) ? 1.f : 0.f;
      }
    for (int k = 0; k < 3; ++k) {
      float alpha = a[k][k];
      float xn2 = 0.f;
      for (int i = k + 1; i < 3; ++i) xn2 += a[i][k] * a[i][k];
      float nrm = sqrtf(alpha * alpha + xn2);
      if (xn2 > 0.f && nrm > 0.f) {
        float beta = (alpha >= 0.f) ? -nrm : nrm;
        float tau = (beta - alpha) / beta;
        float inv = 1.f / (alpha - beta);
        float v[3] = {0.f, 0.f, 0.f};
        v[k] = 1.f;
        for (int i = k + 1; i < 3; ++i) v[i] = a[i][k] * inv;
        for (int j = k; j < 3; ++j) {
          float w = 0.f;
          for (int i = k; i < 3; ++i) w += v[i] * a[i][j];
          w *= tau;
          for (int i = k; i < 3; ++i) a[i][j] -= w * v[i];
        }
        for (int i = 0; i < 3; ++i) {
          float w = 0.f;
          for (int j = k; j < 3; ++j) w += q[i][j] * v[j];
          w *= tau;
          for (int j = k; j < 3; ++j) q[i][j] -= w * v[j];
        }
      }
    }
    for (int i = 0; i < 3; ++i)
      for (int j = 0; j < 3; ++j) Qs[i][j] = q[i][j];
  }
  __syncthreads();
  int b = bt >> 4;
  int l = threadIdx.x;
  float cx = lig_coord[(b * L_ + l) * 3 + 0];
  float cy = lig_coord[(b * L_ + l) * 3 + 1];
  float cz = lig_coord[(b * L_ + l) * 3 + 2];
  float nx = Qs[0][0] * cx + Qs[0][1] * cy + Qs[0][2] * cz + trans[bt * 3 + 0];
  float ny = Qs[1][0] * cx + Qs[1][1] * cy + Qs[1][2] * cz + trans[bt * 3 + 1];
  float nz = Qs[2][0] * cx + Qs[2][1] * cy + Qs[2][2] * cz + trans[bt * 3 + 2];
  float* o = new_lig + ((size_t)bt * L_ + l) * 3;
  o[0] = nx; o[1] = ny; o[2] = nz;
}

// ---------------------------------------------------------------------------
// Kernel 2: atn[b,e,l,r] = sum_f lig_feat[b,l,e,f] * rec_feat[b,r,e,f]
// NO LDS, NO BARRIERS. Round-2's LDS pipeline ran at 1.7 TB/s with all pipes
// idle (MfmaUtil 2.8, VALUBusy 7): the load->sync->vmcnt(0)->write->sync->MFMA
// chain serialized on HBM latency. Here each lane loads its MFMA fragment
// (8 contiguous fp32) straight from global (A is L2-hot at 256 KB/(b,e);
// B-chunk reuse window is L1/L2-resident), converts to bf16 in-register, and
// feeds MFMA. 1-deep explicit prefetch; waves fully independent.
// Tile: M=128 x N=64 per block, wave = 32M x 64N. K in 16 chunks of 32.
// ---------------------------------------------------------------------------
__launch_bounds__(256)
__global__ void gemm_kernel(const float* __restrict__ lig_feat,
                            const float* __restrict__ rec_feat,
                            const int* __restrict__ rec_counts,
                            float* __restrict__ atn) {
  const int rt = blockIdx.x;    // 0..15
  const int e  = blockIdx.y;    // 0..4
  const int b  = blockIdx.z;    // 0..7
  const int r0 = rt * 64;
  if (r0 >= rec_counts[b]) return;   // tile fully masked downstream

  const int tid  = threadIdx.x;
  const int wave = tid >> 6;
  const int lane = tid & 63;
  const int lrow = lane & 15;
  const int quad = lane >> 4;
  const int wm   = wave * 32;        // wave's M-row base

  // fragment row pointers (col offset quad*8 folded in)
  const float* aP[2];
  #pragma unroll
  for (int i = 0; i < 2; ++i)
    aP[i] = lig_feat + ((size_t)(b * L_ + wm + i * 16 + lrow) * E_ + e) * F_ + quad * 8;
  const float* bP[4];
  #pragma unroll
  for (int j = 0; j < 4; ++j)
    bP[j] = rec_feat + ((size_t)(b * R_ + r0 + j * 16 + lrow) * E_ + e) * F_ + quad * 8;

  floatx4 acc[2][4];
  #pragma unroll
  for (int i = 0; i < 2; ++i)
    #pragma unroll
    for (int j = 0; j < 4; ++j)
      acc[i][j] = (floatx4){0.f, 0.f, 0.f, 0.f};

  // prefetch chunk 0
  floatx4 aC[2][2], bC[4][2];
  #pragma unroll
  for (int i = 0; i < 2; ++i) {
    aC[i][0] = *(const floatx4*)(aP[i] + 0);
    aC[i][1] = *(const floatx4*)(aP[i] + 4);
  }
  #pragma unroll
  for (int j = 0; j < 4; ++j) {
    bC[j][0] = *(const floatx4*)(bP[j] + 0);
    bC[j][1] = *(const floatx4*)(bP[j] + 4);
  }

  #pragma unroll 1
  for (int kc = 0; kc < 16; ++kc) {
    floatx4 aN[2][2], bN[4][2];
    if (kc < 15) {
      const int col = (kc + 1) * 32;
      #pragma unroll
      for (int i = 0; i < 2; ++i) {
        aN[i][0] = *(const floatx4*)(aP[i] + col);
        aN[i][1] = *(const floatx4*)(aP[i] + col + 4);
      }
      #pragma unroll
      for (int j = 0; j < 4; ++j) {
        bN[j][0] = *(const floatx4*)(bP[j] + col);
        bN[j][1] = *(const floatx4*)(bP[j] + col + 4);
      }
    }
    short8 af[2], bfv[4];
    #pragma unroll
    for (int i = 0; i < 2; ++i) af[i] = pack8(aC[i][0], aC[i][1]);
    #pragma unroll
    for (int j = 0; j < 4; ++j) bfv[j] = pack8(bC[j][0], bC[j][1]);
    #pragma unroll
    for (int i = 0; i < 2; ++i)
      #pragma unroll
      for (int j = 0; j < 4; ++j)
        acc[i][j] = __builtin_amdgcn_mfma_f32_16x16x32_bf16(af[i], bfv[j], acc[i][j], 0, 0, 0);
    #pragma unroll
    for (int i = 0; i < 2; ++i) { aC[i][0] = aN[i][0]; aC[i][1] = aN[i][1]; }
    #pragma unroll
    for (int j = 0; j < 4; ++j) { bC[j][0] = bN[j][0]; bC[j][1] = bN[j][1]; }
  }

  // store C tile: atn[((b*E+e)*L + m)*R + r0 + n]; C/D: col=lane&15, row=quad*4+reg
  const size_t base = (size_t)(b * E_ + e) * L_ * R_;
  #pragma unroll
  for (int i = 0; i < 2; ++i)
    #pragma unroll
    for (int j = 0; j < 4; ++j)
      #pragma unroll
      for (int reg = 0; reg < 4; ++reg) {
        int m = wm + i * 16 + quad * 4 + reg;
        int n = j * 16 + lrow;
        atn[base + (size_t)m * R_ + r0 + n] = acc[i][j][reg];
      }
}

// ---------------------------------------------------------------------------
// Kernel 3: partial[b,t,l] = sum_{r,e} atn[b,e,l,r] * d(b,t,l,r)^exp[e]
// One block per (b,l), no atomics. Explicit next-chunk load prefetch so the
// 8 independent loads overlap the ~300-op t-loop compute.
// ---------------------------------------------------------------------------
__launch_bounds__(256)
__global__ void reduce_kernel(const float* __restrict__ atn,
                              const float* __restrict__ new_lig,
                              const float* __restrict__ rec_coord,
                              const int* __restrict__ lig_counts,
                              const int* __restrict__ rec_counts,
                              float* __restrict__ partial) {
  const int b = blockIdx.x >> 7;
  const int l = blockIdx.x & 127;
  const int tid = threadIdx.x;
  if (l >= lig_counts[b]) {             // write zeros so final_kernel is mask-free
    if (tid < T_) partial[(size_t)(b * T_ + tid) * L_ + l] = 0.f;
    return;
  }
  const int recN = rec_counts[b];
  const int rrEnd = (recN + 255) >> 8;

  __shared__ float nl[T_][3];
  __shared__ float sm[4][T_];
  if (tid < T_ * 3)
    nl[tid / 3][tid % 3] =
        new_lig[((size_t)(b * T_ + tid / 3) * L_ + l) * 3 + (tid % 3)];
  __syncthreads();

  float u[T_];
  #pragma unroll
  for (int t = 0; t < T_; ++t) u[t] = 0.f;

  const size_t plane = (size_t)L_ * R_;
  const float* atnB = atn + (size_t)b * E_ * plane + (size_t)l * R_;
  const float* rcB  = rec_coord + (size_t)b * R_ * 3;

  // prefetch chunk 0
  float a[5], rc[3];
  {
    const int r = tid;
    #pragma unroll
    for (int e = 0; e < 5; ++e) a[e] = atnB[e * plane + r];
    #pragma unroll
    for (int c = 0; c < 3; ++c) rc[c] = rcB[r * 3 + c];
  }

  for (int rr = 0; rr < rrEnd; ++rr) {
    float an[5], rcn[3];
    if (rr + 1 < rrEnd) {
      const int r = tid + (rr + 1) * 256;
      #pragma unroll
      for (int e = 0; e < 5; ++e) an[e] = atnB[e * plane + r];
      #pragma unroll
      for (int c = 0; c < 3; ++c) rcn[c] = rcB[r * 3 + c];
    }
    const int r = tid + rr * 256;
    const float msk = (r < recN) ? 1.f : 0.f;
    const float a0 = a[0] * msk, a1 = a[1] * msk, a2 = a[2] * msk;
    const float a3 = a[3] * msk, a4 = a[4] * msk;
    #pragma unroll
    for (int t = 0; t < T_; ++t) {
      float dx = nl[t][0] - rc[0];
      float dy = nl[t][1] - rc[1];
      float dz = nl[t][2] - rc[2];
      float d2 = fmaf(dx, dx, fmaf(dy, dy, dz * dz));
      d2 = fmaxf(d2, 1e-20f);
      float rs  = rsqrtf(d2);
      float rs2 = rs * rs;
      float rs3 = rs2 * rs;
      float d1  = d2 * rs;
      float c = a0 * rs3;
      c = fmaf(a1, rs2, c);
      c = fmaf(a2, rs, c);
      c = fmaf(a3, d1, c);
      c = fmaf(a4, d2, c);
      u[t] += c;
    }
    #pragma unroll
    for (int e = 0; e < 5; ++e) a[e] = an[e];
    #pragma unroll
    for (int c = 0; c < 3; ++c) rc[c] = rcn[c];
  }

  const int wave = tid >> 6;
  #pragma unroll
  for (int t = 0; t < T_; ++t) {
    float v = u[t];
    #pragma unroll
    for (int m = 32; m > 0; m >>= 1) v += __shfl_xor(v, m, 64);
    if ((tid & 63) == 0) sm[wave][t] = v;
  }
  __syncthreads();
  if (tid < T_)
    partial[(size_t)(b * T_ + tid) * L_ + l] =
        sm[0][tid] + sm[1][tid] + sm[2][tid] + sm[3][tid];
}

// ---------------------------------------------------------------------------
// Kernel 4: out[b,t] = sum_l partial[b,t,l]   (128 blocks x 128 threads)
// ---------------------------------------------------------------------------
__global__ void final_kernel(const float* __restrict__ partial,
                             float* __restrict__ out) {
  const int bt = blockIdx.x;
  const int l = threadIdx.x;
  float v = partial[(size_t)bt * L_ + l];
  #pragma unroll
  for (int m = 32; m > 0; m >>= 1) v += __shfl_xor(v, m, 64);
  __shared__ float s[2];
  if ((l & 63) == 0) s[l >> 6] = v;
  __syncthreads();
  if (l == 0) out[bt] = s[0] + s[1];
}

// ---------------------------------------------------------------------------
extern "C" void kernel_launch(void* const* d_in, const int* in_sizes, int n_in,
                              void* d_out, int out_size, void* d_ws, size_t ws_size,
                              hipStream_t stream) {
  const float* lig_feat   = (const float*)d_in[0];
  const float* rec_feat   = (const float*)d_in[1];
  const float* lig_coord  = (const float*)d_in[2];
  const float* rec_coord  = (const float*)d_in[3];
  const float* pre_rot    = (const float*)d_in[4];
  const float* trans      = (const float*)d_in[5];
  const int*   lig_counts = (const int*)d_in[6];
  const int*   rec_counts = (const int*)d_in[7];
  float* out = (float*)d_out;

  // ws: new_lig [B,T,L,3] | atn [B,E,L,R] | partial [B,T,L]  (~21.3 MB fp32)
  float* new_lig = (float*)d_ws;
  float* atn     = new_lig + (size_t)B_ * T_ * L_ * 3;
  float* partial = atn + (size_t)B_ * E_ * L_ * R_;

  prep_kernel<<<dim3(B_ * T_), dim3(L_), 0, stream>>>(lig_coord, pre_rot, trans, new_lig);
  gemm_kernel<<<dim3(R_ / 64, E_, B_), dim3(256), 0, stream>>>(lig_feat, rec_feat,
                                                               rec_counts, atn);
  reduce_kernel<<<dim3(B_ * L_), dim3(256), 0, stream>>>(atn, new_lig, rec_coord,
                                                         lig_counts, rec_counts, partial);
  final_kernel<<<dim3(B_ * T_), dim3(128), 0, stream>>>(partial, out);
}

// Round 4
// 170.134 us; speedup vs baseline: 1.2241x; 1.2241x over previous
//
#include <hip/hip_runtime.h>
#include <hip/hip_bf16.h>

// Problem constants (from reference): B,T,L,R,E,F
#define B_ 8
#define T_ 16
#define L_ 128
#define R_ 1024
#define E_ 5
#define F_ 512

typedef short short8 __attribute__((ext_vector_type(8)));
typedef float floatx4 __attribute__((ext_vector_type(4)));

// fp32 -> bf16 bits, round-half-up
__device__ __forceinline__ unsigned short f2bf(float f) {
  unsigned u = __float_as_uint(f);
  return (unsigned short)((u + 0x8000u) >> 16);
}

__device__ __forceinline__ short8 pack8(floatx4 lo, floatx4 hi) {
  short8 v;
  v[0] = (short)f2bf(lo[0]); v[1] = (short)f2bf(lo[1]);
  v[2] = (short)f2bf(lo[2]); v[3] = (short)f2bf(lo[3]);
  v[4] = (short)f2bf(hi[0]); v[5] = (short)f2bf(hi[1]);
  v[6] = (short)f2bf(hi[2]); v[7] = (short)f2bf(hi[3]);
  return v;
}

// async 16B global->LDS DMA; lane i's data lands at ldsbase + i*16
__device__ __forceinline__ void stage16(const float* g, float* lds) {
  __builtin_amdgcn_global_load_lds(
      (const __attribute__((address_space(1))) void*)g,
      (__attribute__((address_space(3))) void*)lds, 16, 0, 0);
}

// ---------------------------------------------------------------------------
// Kernel 1: rot = QR(pre_rot).Q (LAPACK Householder convention), then
// new_lig[b,t,l,:] = rot[b,t] @ lig_coord[b,l] + trans[b,t].
// ---------------------------------------------------------------------------
__global__ void prep_kernel(const float* __restrict__ lig_coord,
                            const float* __restrict__ pre_rot,
                            const float* __restrict__ trans,
                            float* __restrict__ new_lig) {
  int bt = blockIdx.x;
  __shared__ float Qs[3][3];
  if (threadIdx.x == 0) {
    float a[3][3], q[3][3];
    #pragma unroll
    for (int i = 0; i < 3; ++i)
      #pragma unroll
      for (int j = 0; j < 3; ++j) {
        a[i][j] = pre_rot[(bt * 3 + i) * 3 + j];
        q[i][j] = (i == j) ? 1.f : 0.f;
      }
    for (int k = 0; k < 3; ++k) {
      float alpha = a[k][k];
      float xn2 = 0.f;
      for (int i = k + 1; i < 3; ++i) xn2 += a[i][k] * a[i][k];
      float nrm = sqrtf(alpha * alpha + xn2);
      if (xn2 > 0.f && nrm > 0.f) {
        float beta = (alpha >= 0.f) ? -nrm : nrm;
        float tau = (beta - alpha) / beta;
        float inv = 1.f / (alpha - beta);
        float v[3] = {0.f, 0.f, 0.f};
        v[k] = 1.f;
        for (int i = k + 1; i < 3; ++i) v[i] = a[i][k] * inv;
        for (int j = k; j < 3; ++j) {
          float w = 0.f;
          for (int i = k; i < 3; ++i) w += v[i] * a[i][j];
          w *= tau;
          for (int i = k; i < 3; ++i) a[i][j] -= w * v[i];
        }
        for (int i = 0; i < 3; ++i) {
          float w = 0.f;
          for (int j = k; j < 3; ++j) w += q[i][j] * v[j];
          w *= tau;
          for (int j = k; j < 3; ++j) q[i][j] -= w * v[j];
        }
      }
    }
    for (int i = 0; i < 3; ++i)
      for (int j = 0; j < 3; ++j) Qs[i][j] = q[i][j];
  }
  __syncthreads();
  int b = bt >> 4;
  int l = threadIdx.x;
  float cx = lig_coord[(b * L_ + l) * 3 + 0];
  float cy = lig_coord[(b * L_ + l) * 3 + 1];
  float cz = lig_coord[(b * L_ + l) * 3 + 2];
  float nx = Qs[0][0] * cx + Qs[0][1] * cy + Qs[0][2] * cz + trans[bt * 3 + 0];
  float ny = Qs[1][0] * cx + Qs[1][1] * cy + Qs[1][2] * cz + trans[bt * 3 + 1];
  float nz = Qs[2][0] * cx + Qs[2][1] * cy + Qs[2][2] * cz + trans[bt * 3 + 2];
  float* o = new_lig + ((size_t)bt * L_ + l) * 3;
  o[0] = nx; o[1] = ny; o[2] = nz;
}

// ---------------------------------------------------------------------------
// Kernel 2: atn[b,e,l,r] = sum_f lig_feat[b,l,e,f] * rec_feat[b,r,e,f]
// m97-style: global_load_lds(16B) DMA staging of fp32 into DOUBLE-BUFFERED
// LDS (BK=32: A 16KB + B 8KB per buf, 48KB total -> 3 blocks/CU), one barrier
// per chunk so chunk k+1's HBM latency hides under chunk k's compute.
// Swizzle is applied on the GLOBAL source address (16B-chunk ^= row&7, the
// R2 scheme that measured 0 conflicts) because the LDS side of the DMA is
// fixed linear base+lane*16. bf16 conversion happens at fragment read.
// Tile: M=128 x N=64 per block (640 blocks); wave = 32M x 64N.
// ---------------------------------------------------------------------------
__launch_bounds__(256)
__global__ void gemm_kernel(const float* __restrict__ lig_feat,
                            const float* __restrict__ rec_feat,
                            const int* __restrict__ rec_counts,
                            float* __restrict__ atn) {
  const int rt = blockIdx.x;    // 0..15
  const int e  = blockIdx.y;    // 0..4
  const int b  = blockIdx.z;    // 0..7
  const int r0 = rt * 64;
  if (r0 >= rec_counts[b]) return;   // tile fully masked downstream

  __shared__ float As[2][128 * 32];  // [buf][row][32k], 16B chunks swizzled
  __shared__ float Bs[2][64 * 32];

  const int tid  = threadIdx.x;
  const int wave = tid >> 6;
  const int lane = tid & 63;
  const int lrow = lane & 15;
  const int quad = lane >> 4;
  const int wm   = wave * 32;

  // --- staging source addresses (per lane) ---
  // wave stages 8 rows per instr: lane -> row = rowbase + (lane>>3),
  // physical 16B chunk (lane&7) holds global chunk (lane&7)^(row&7).
  const int lr8 = lane >> 3;
  const int sw  = (lane & 7) ^ lr8;      // global 16B-chunk index to fetch
  const float* ga[4];
  #pragma unroll
  for (int i = 0; i < 4; ++i) {
    int row = wave * 32 + i * 8 + lr8;
    ga[i] = lig_feat + ((size_t)(b * L_ + row) * E_ + e) * F_ + sw * 4;
  }
  const float* gb[2];
  #pragma unroll
  for (int i = 0; i < 2; ++i) {
    int row = wave * 16 + i * 8 + lr8;
    gb[i] = rec_feat + ((size_t)(b * R_ + r0 + row) * E_ + e) * F_ + sw * 4;
  }

  floatx4 acc[2][4];
  #pragma unroll
  for (int i = 0; i < 2; ++i)
    #pragma unroll
    for (int j = 0; j < 4; ++j)
      acc[i][j] = (floatx4){0.f, 0.f, 0.f, 0.f};

  // fragment-read physical chunks: global chunk 2*quad (+1) at ^(row&7);
  // row&7 == lane&7 for all fragment rows (wm, i*16, j*16 are multiples of 8)
  const int c0 = (2 * quad) ^ (lane & 7);

  // stage chunk 0 -> buf 0
  #pragma unroll
  for (int i = 0; i < 4; ++i) stage16(ga[i], &As[0][(wave * 32 + i * 8) * 32]);
  #pragma unroll
  for (int i = 0; i < 2; ++i) stage16(gb[i], &Bs[0][(wave * 16 + i * 8) * 32]);
  __syncthreads();   // vmcnt(0) drain: buf0 ready

  #pragma unroll 1
  for (int kc = 0; kc < 16; ++kc) {
    const int cur = kc & 1;
    if (kc < 15) {   // async-stage next chunk into the other buffer
      const int col = (kc + 1) * 32;
      #pragma unroll
      for (int i = 0; i < 4; ++i)
        stage16(ga[i] + col, &As[cur ^ 1][(wave * 32 + i * 8) * 32]);
      #pragma unroll
      for (int i = 0; i < 2; ++i)
        stage16(gb[i] + col, &Bs[cur ^ 1][(wave * 16 + i * 8) * 32]);
    }
    short8 af[2], bfv[4];
    #pragma unroll
    for (int i = 0; i < 2; ++i) {
      const float* base = &As[cur][(wm + i * 16 + lrow) * 32];
      af[i] = pack8(*(const floatx4*)(base + c0 * 4),
                    *(const floatx4*)(base + (c0 ^ 1) * 4));
    }
    #pragma unroll
    for (int j = 0; j < 4; ++j) {
      const float* base = &Bs[cur][(j * 16 + lrow) * 32];
      bfv[j] = pack8(*(const floatx4*)(base + c0 * 4),
                     *(const floatx4*)(base + (c0 ^ 1) * 4));
    }
    #pragma unroll
    for (int i = 0; i < 2; ++i)
      #pragma unroll
      for (int j = 0; j < 4; ++j)
        acc[i][j] = __builtin_amdgcn_mfma_f32_16x16x32_bf16(af[i], bfv[j], acc[i][j], 0, 0, 0);
    __syncthreads();  // waves done reading buf[cur]; stage(kc+1) drained
  }

  // store C tile: atn[((b*E+e)*L + m)*R + r0 + n]; C/D: col=lane&15, row=quad*4+reg
  const size_t base = (size_t)(b * E_ + e) * L_ * R_;
  #pragma unroll
  for (int i = 0; i < 2; ++i)
    #pragma unroll
    for (int j = 0; j < 4; ++j)
      #pragma unroll
      for (int reg = 0; reg < 4; ++reg) {
        int m = wm + i * 16 + quad * 4 + reg;
        int n = j * 16 + lrow;
        atn[base + (size_t)m * R_ + r0 + n] = acc[i][j][reg];
      }
}

// ---------------------------------------------------------------------------
// Kernel 3: partial[b,t,l] = sum_{r,e} atn[b,e,l,r] * d(b,t,l,r)^exp[e]
// One block per (b,l). Single pass: thread owns r = 4*tid..+4 (float4 loads,
// all 8 16B loads issue at once -> latency amortized over ~960 FLOP).
// Wave-uniform skip of fully-masked 256-r spans. No atomics.
// ---------------------------------------------------------------------------
__launch_bounds__(256)
__global__ void reduce_kernel(const float* __restrict__ atn,
                              const float* __restrict__ new_lig,
                              const float* __restrict__ rec_coord,
                              const int* __restrict__ lig_counts,
                              const int* __restrict__ rec_counts,
                              float* __restrict__ partial) {
  const int b = blockIdx.x >> 7;
  const int l = blockIdx.x & 127;
  const int tid = threadIdx.x;
  if (l >= lig_counts[b]) {             // write zeros so final_kernel is mask-free
    if (tid < T_) partial[(size_t)(b * T_ + tid) * L_ + l] = 0.f;
    return;
  }
  const int recN = rec_counts[b];
  const int wave = tid >> 6;

  __shared__ float nl[T_][3];
  __shared__ float sm[4][T_];
  if (tid < T_ * 3)
    nl[tid / 3][tid % 3] =
        new_lig[((size_t)(b * T_ + tid / 3) * L_ + l) * 3 + (tid % 3)];
  __syncthreads();

  float u[T_];
  #pragma unroll
  for (int t = 0; t < T_; ++t) u[t] = 0.f;

  if (wave * 256 < recN) {              // wave-uniform skip of masked span
    const int r = tid * 4;
    const size_t plane = (size_t)L_ * R_;
    const float* atnB = atn + (size_t)b * E_ * plane + (size_t)l * R_ + r;
    const float* rcB  = rec_coord + ((size_t)b * R_ + r) * 3;

    floatx4 a4[5];
    #pragma unroll
    for (int e = 0; e < 5; ++e) a4[e] = *(const floatx4*)(atnB + e * plane);
    floatx4 q0 = *(const floatx4*)(rcB + 0);
    floatx4 q1 = *(const floatx4*)(rcB + 4);
    floatx4 q2 = *(const floatx4*)(rcB + 8);
    float px[4] = {q0[0], q0[3], q1[2], q2[1]};
    float py[4] = {q0[1], q1[0], q1[3], q2[2]};
    float pz[4] = {q0[2], q1[1], q2[0], q2[3]};
    float am[5][4];
    #pragma unroll
    for (int e = 0; e < 5; ++e)
      #pragma unroll
      for (int s = 0; s < 4; ++s)
        am[e][s] = (r + s < recN) ? a4[e][s] : 0.f;

    #pragma unroll
    for (int t = 0; t < T_; ++t) {
      float acc = 0.f;
      #pragma unroll
      for (int s = 0; s < 4; ++s) {
        float dx = nl[t][0] - px[s];
        float dy = nl[t][1] - py[s];
        float dz = nl[t][2] - pz[s];
        float d2 = fmaf(dx, dx, fmaf(dy, dy, dz * dz));
        d2 = fmaxf(d2, 1e-20f);
        float rs  = rsqrtf(d2);
        float rs2 = rs * rs;
        float rs3 = rs2 * rs;
        float d1  = d2 * rs;
        float c = am[0][s] * rs3;
        c = fmaf(am[1][s], rs2, c);
        c = fmaf(am[2][s], rs, c);
        c = fmaf(am[3][s], d1, c);
        c = fmaf(am[4][s], d2, c);
        acc += c;
      }
      u[t] += acc;
    }
  }

  #pragma unroll
  for (int t = 0; t < T_; ++t) {
    float v = u[t];
    #pragma unroll
    for (int m = 32; m > 0; m >>= 1) v += __shfl_xor(v, m, 64);
    if ((tid & 63) == 0) sm[wave][t] = v;
  }
  __syncthreads();
  if (tid < T_)
    partial[(size_t)(b * T_ + tid) * L_ + l] =
        sm[0][tid] + sm[1][tid] + sm[2][tid] + sm[3][tid];
}

// ---------------------------------------------------------------------------
// Kernel 4: out[b,t] = sum_l partial[b,t,l]   (128 blocks x 128 threads)
// ---------------------------------------------------------------------------
__global__ void final_kernel(const float* __restrict__ partial,
                             float* __restrict__ out) {
  const int bt = blockIdx.x;
  const int l = threadIdx.x;
  float v = partial[(size_t)bt * L_ + l];
  #pragma unroll
  for (int m = 32; m > 0; m >>= 1) v += __shfl_xor(v, m, 64);
  __shared__ float s[2];
  if ((l & 63) == 0) s[l >> 6] = v;
  __syncthreads();
  if (l == 0) out[bt] = s[0] + s[1];
}

// ---------------------------------------------------------------------------
extern "C" void kernel_launch(void* const* d_in, const int* in_sizes, int n_in,
                              void* d_out, int out_size, void* d_ws, size_t ws_size,
                              hipStream_t stream) {
  const float* lig_feat   = (const float*)d_in[0];
  const float* rec_feat   = (const float*)d_in[1];
  const float* lig_coord  = (const float*)d_in[2];
  const float* rec_coord  = (const float*)d_in[3];
  const float* pre_rot    = (const float*)d_in[4];
  const float* trans      = (const float*)d_in[5];
  const int*   lig_counts = (const int*)d_in[6];
  const int*   rec_counts = (const int*)d_in[7];
  float* out = (float*)d_out;

  // ws: new_lig [B,T,L,3] | atn [B,E,L,R] | partial [B,T,L]  (~21.3 MB fp32)
  float* new_lig = (float*)d_ws;
  float* atn     = new_lig + (size_t)B_ * T_ * L_ * 3;
  float* partial = atn + (size_t)B_ * E_ * L_ * R_;

  prep_kernel<<<dim3(B_ * T_), dim3(L_), 0, stream>>>(lig_coord, pre_rot, trans, new_lig);
  gemm_kernel<<<dim3(R_ / 64, E_, B_), dim3(256), 0, stream>>>(lig_feat, rec_feat,
                                                               rec_counts, atn);
  reduce_kernel<<<dim3(B_ * L_), dim3(256), 0, stream>>>(atn, new_lig, rec_coord,
                                                         lig_counts, rec_counts, partial);
  final_kernel<<<dim3(B_ * T_), dim3(128), 0, stream>>>(partial, out);
}